// Round 11
// baseline (261.847 us; speedup 1.0000x reference)
//
#include <hip/hip_runtime.h>

#define Bz 4
#define Tz 4096
#define Ez 1024
#define Hz 16
#define Sz 64
#define Dz 64
#define MTz (Bz*Tz)   // 16384

using f32x4  = __attribute__((ext_vector_type(4))) float;
using short8 = __attribute__((ext_vector_type(8))) short;

__device__ __forceinline__ unsigned f2bf(float f){
  unsigned u = __builtin_bit_cast(unsigned, f);
  u = u + 0x7FFFu + ((u >> 16) & 1u);
  return (u >> 16);
}

#define GLL16(gp, lp) __builtin_amdgcn_global_load_lds( \
    (const __attribute__((address_space(1))) unsigned int*)(gp), \
    (__attribute__((address_space(3))) unsigned int*)(lp), 16, 0, 0)

// ---------------- K1 (64 blocks): Mh, smB_g (pre-swizzled), a_state+bias_f -----------
__global__ __launch_bounds__(256) void k1_pre(const float* __restrict__ state,
                                              const float* __restrict__ A_w,
                                              const float* __restrict__ A_b,
                                              const float* __restrict__ C_w,
                                              const float* __restrict__ C_b,
                                              const float* __restrict__ sm,
                                              float* __restrict__ a_state,
                                              float* __restrict__ Mh,
                                              float* __restrict__ bias_f,
                                              unsigned short* __restrict__ smB_g){
  __shared__ float asl[4][64];
  const int blk = blockIdx.x, tid = threadIdx.x;
  const int h = blk >> 2, q4 = blk & 3;
  { // Mh[h][d][dp] quarter
    const int d = q4*16 + (tid >> 4), dp0 = (tid & 15)*4;
    const float* cw  = C_w + (size_t)(h*64 + d)*64;
    const float* smh = sm + (size_t)h*4096 + dp0;
    float ax=0.f, ay=0.f, az=0.f, aw=0.f;
    #pragma unroll 8
    for (int s = 0; s < 64; ++s){
      float c = cw[s];
      float4 m4 = *(const float4*)&smh[s*64];
      ax += c*m4.x; ay += c*m4.y; az += c*m4.z; aw += c*m4.w;
    }
    *(float4*)&Mh[(size_t)h*4096 + d*64 + dp0] = make_float4(ax,ay,az,aw);
  }
  if (tid < 128){ // smB_g: bf16 cast of sm[h], stored pre-swizzled: slot=(s*4+g)^(s&7)
    int chunk = q4*128 + tid;            // (s, seg) chunk of 8 elems
    int s = chunk >> 3, seg = chunk & 7;
    int half = seg >> 2, g2 = seg & 3;
    int b2 = (s & 1) ^ ((s >> 2) & 1);   // bit2 of swizzled slot
    int l10 = g2 ^ ((((s >> 1) & 1) << 1) | (s & 1));
    int L = ((s >> 1) << 3) | (b2 << 2) | l10;
    const float* ps = sm + (size_t)h*4096 + s*64 + seg*8;
    float4 v0 = *(const float4*)ps, v1 = *(const float4*)(ps + 4);
    uint4 pk;
    pk.x = f2bf(v0.x) | (f2bf(v0.y)<<16);
    pk.y = f2bf(v0.z) | (f2bf(v0.w)<<16);
    pk.z = f2bf(v1.x) | (f2bf(v1.y)<<16);
    pk.w = f2bf(v1.z) | (f2bf(v1.w)<<16);
    *(uint4*)&smB_g[((size_t)h*512 + half*256 + L)*8] = pk;
  }
  if (q4 == 0){
    { // a_state[h][b][s]
      const int b = tid >> 6, s = tid & 63;
      const float* aw = A_w + (size_t)(h*64 + s)*64;
      const float* st = state + (size_t)(h*4 + b)*64;
      float a0=A_b[h*64+s], a1=0.f, a2=0.f, a3=0.f;
      #pragma unroll 4
      for (int j = 0; j < 64; j += 4){
        a0 += aw[j]*st[j]; a1 += aw[j+1]*st[j+1];
        a2 += aw[j+2]*st[j+2]; a3 += aw[j+3]*st[j+3];
      }
      float v = (a0+a1)+(a2+a3);
      a_state[(h*4 + b)*64 + s] = v;
      asl[b][s] = v;
    }
    __syncthreads();
    { // bias_f[b][h*64+d]
      const int b = tid >> 6, d = tid & 63;
      const float* cw = C_w + (size_t)(h*64 + d)*64;
      float a0=C_b[h*64+d], a1=0.f, a2=0.f, a3=0.f;
      #pragma unroll 4
      for (int s = 0; s < 64; s += 4){
        a0 += cw[s]*asl[b][s]; a1 += cw[s+1]*asl[b][s+1];
        a2 += cw[s+2]*asl[b][s+2]; a3 += cw[s+3]*asl[b][s+3];
      }
      bias_f[b*1024 + h*64 + d] = (a0+a1)+(a2+a3);
    }
  }
}

// ---------------- K23 (2048 blocks): Wb (0..1023) ; constb (1024..2047) --------------
__global__ __launch_bounds__(256) void k23_pre(const float* __restrict__ Wo,
                                               const float* __restrict__ Mh,
                                               const float* __restrict__ bias_f,
                                               const float* __restrict__ bo,
                                               unsigned short* __restrict__ Wb,
                                               float* __restrict__ constb){
  const int blk = blockIdx.x, tid = threadIdx.x;
  if (blk < 1024){
    __shared__ float Mh_l[4096];
    const int h = blk >> 6, ec = blk & 63;
    #pragma unroll
    for (int it = 0; it < 4; ++it){
      int c = it*256 + tid;
      *(float4*)&Mh_l[c*4] = *(const float4*)&Mh[(size_t)h*4096 + c*4];
    }
    __syncthreads();
    const int dp = tid & 63, er = tid >> 6;
    #pragma unroll
    for (int ee = 0; ee < 4; ++ee){
      const int e = ec*16 + er*4 + ee;
      const float* wo = Wo + (size_t)e*1024 + h*64;
      float a0=0.f,a1=0.f,a2=0.f,a3=0.f;
      #pragma unroll 4
      for (int d = 0; d < 64; d += 4){
        a0 += wo[d]*Mh_l[d*64+dp];     a1 += wo[d+1]*Mh_l[(d+1)*64+dp];
        a2 += wo[d+2]*Mh_l[(d+2)*64+dp]; a3 += wo[d+3]*Mh_l[(d+3)*64+dp];
      }
      Wb[(size_t)e*1024 + h*64 + dp] = (unsigned short)f2bf((a0+a1)+(a2+a3));
    }
  } else {
    const int idx = (blk - 1024)*4 + (tid >> 6), lane = tid & 63;
    const int b = idx >> 10, e = idx & 1023;
    const float4* wo = (const float4*)(Wo + (size_t)e*1024);
    const float4* bf = (const float4*)(bias_f + (size_t)b*1024);
    float acc = 0.f;
    #pragma unroll
    for (int i = 0; i < 4; ++i){
      float4 w = wo[i*64 + lane], v = bf[i*64 + lane];
      acc += w.x*v.x + w.y*v.y + w.z*v.z + w.w*v.w;
    }
    acc += __shfl_down(acc, 32); acc += __shfl_down(acc, 16); acc += __shfl_down(acc, 8);
    acc += __shfl_down(acc, 4);  acc += __shfl_down(acc, 2);  acc += __shfl_down(acc, 1);
    if (lane == 0) constb[b*1024 + e] = bo[e] + acc;
  }
}

// ---------------- MEGA (256 blocks x 512): out = bf16(x)@Wb^T + const ; out2 fused ---
// A: reg-staged from x f32 (cvt in-kernel), 2-deep LDS. B: 4-deep GLL (R3 schedule).
// out2: on 8 "active" k-tiles per block (head-group = bn-group), extra 8 MFMA/tile.
// launch_bounds (512,1): LDS (129KB) already forces 1 block/CU; min-waves=1 lets the
// allocator use up to 256 VGPR (2 waves/SIMD) instead of spilling at the 128 cap (R8).
__global__ __launch_bounds__(512, 1) void mega(const float* __restrict__ x,
                                               const unsigned short* __restrict__ Wb,
                                               const unsigned short* __restrict__ smB_g,
                                               const float* __restrict__ a_state,
                                               const float* __restrict__ constb,
                                               float* __restrict__ out,
                                               float* __restrict__ out2){
  __shared__ alignas(16) unsigned short ldsA[2][8192];
  __shared__ alignas(16) unsigned short ldsB[4][8192];
  __shared__ alignas(16) unsigned short ldsS[16384];
  __shared__ float ldsAS[256];
  const int blk = blockIdx.x;
  const int swz = (blk & 7)*32 + (blk >> 3);
  const int bm = (swz >> 2)*256, hq = swz & 3, bn = hq*256;
  const int bb = bm >> 12;
  const int tid = threadIdx.x;
  const int lane = tid & 63, w = tid >> 6;
  const int l15 = lane & 15, l4 = lane >> 4;
  const int wr = w >> 2, wc = w & 3;

  // per-lane (row,seg) decode for staging slot L
  const float* srcAx0; const float* srcAx1;
  const unsigned short* srcB0; const unsigned short* srcB1;
  {
    int L0 = w*64 + lane, L1 = 512 + w*64 + lane;
    int b0 = ((L0>>2)&1) ^ ((L0>>4)&1);
    int r0 = (L0>>3)*2 + b0;
    int g0 = (L0&3) ^ ((((L0>>3)&1)<<1) | b0);
    int b1 = ((L1>>2)&1) ^ ((L1>>4)&1);
    int r1 = (L1>>3)*2 + b1;
    int g1 = (L1&3) ^ ((((L1>>3)&1)<<1) | b1);
    srcAx0 = x + (size_t)(bm + r0)*1024 + g0*8;
    srcAx1 = x + (size_t)(bm + r1)*1024 + g1*8;
    srcB0  = Wb + (size_t)(bn + r0)*1024 + g0*8;
    srcB1  = Wb + (size_t)(bn + r1)*1024 + g1*8;
  }
  const int dstoff = w*512;
  const int lane_off = ((l15*4 + l4) ^ (l15 & 7))*8;

  f32x4 acc[8][4] = {};
  f32x4 acc2[8];
  float4 rAa[4], rAb[4];

  // ---- prologue ----
  if (tid < 64){
    const int hl = tid >> 4, s4 = tid & 15;
    const float4 av = *(const float4*)(a_state + (size_t)((hq*4 + hl)*4 + bb)*64 + s4*4);
    *(float4*)&ldsAS[hl*64 + s4*4] = av;
  }
  rAa[0] = *(const float4*)(srcAx0);
  rAa[1] = *(const float4*)(srcAx0 + 4);
  rAa[2] = *(const float4*)(srcAx1);
  rAa[3] = *(const float4*)(srcAx1 + 4);
  #pragma unroll
  for (int it = 0; it < 4; ++it)
    GLL16(smB_g + ((size_t)(hq*4 + it)*512 + w*64 + lane)*8, &ldsS[(it*512 + w*64)*8]);
  #pragma unroll
  for (int t = 0; t < 3; ++t){
    GLL16(srcB0 + t*32, &ldsB[t][0*4096 + dstoff]);
    GLL16(srcB1 + t*32, &ldsB[t][1*4096 + dstoff]);
  }
  { // ds_write A(0) (implicit vmcnt wait for rAa lands here)
    uint4 p0, p1;
    p0.x = f2bf(rAa[0].x) | (f2bf(rAa[0].y)<<16);
    p0.y = f2bf(rAa[0].z) | (f2bf(rAa[0].w)<<16);
    p0.z = f2bf(rAa[1].x) | (f2bf(rAa[1].y)<<16);
    p0.w = f2bf(rAa[1].z) | (f2bf(rAa[1].w)<<16);
    p1.x = f2bf(rAa[2].x) | (f2bf(rAa[2].y)<<16);
    p1.y = f2bf(rAa[2].z) | (f2bf(rAa[2].w)<<16);
    p1.z = f2bf(rAa[3].x) | (f2bf(rAa[3].y)<<16);
    p1.w = f2bf(rAa[3].z) | (f2bf(rAa[3].w)<<16);
    *(uint4*)(&ldsA[0][0*4096 + w*512 + lane*8]) = p0;
    *(uint4*)(&ldsA[0][1*4096 + w*512 + lane*8]) = p1;
  }
  rAb[0] = *(const float4*)(srcAx0 + 32);
  rAb[1] = *(const float4*)(srcAx0 + 36);
  rAb[2] = *(const float4*)(srcAx1 + 32);
  rAb[3] = *(const float4*)(srcAx1 + 36);
  asm volatile("s_waitcnt vmcnt(4) lgkmcnt(0)" ::: "memory");
  __builtin_amdgcn_s_barrier();
  asm volatile("" ::: "memory");

#define MEGA_TILE(T, CUR, NXT)                                                         \
  {                                                                                    \
    const int t_ = (T);                                                                \
    const unsigned short* At = &ldsA[t_ & 1][0];                                       \
    const unsigned short* Bt = &ldsB[t_ & 3][0];                                       \
    const bool act = (t_ >> 3) == hq;                                                  \
    const int hl = (t_ >> 1) & 3;                                                      \
    if (t_ <= 29){                                                                     \
      NXT[0] = *(const float4*)(srcAx0 + (t_+2)*32);                                   \
      NXT[1] = *(const float4*)(srcAx0 + (t_+2)*32 + 4);                               \
      NXT[2] = *(const float4*)(srcAx1 + (t_+2)*32);                                   \
      NXT[3] = *(const float4*)(srcAx1 + (t_+2)*32 + 4);                               \
    }                                                                                  \
    if (t_ <= 28){                                                                     \
      GLL16(srcB0 + (t_+3)*32, &ldsB[(t_+3)&3][0*4096 + dstoff]);                      \
      GLL16(srcB1 + (t_+3)*32, &ldsB[(t_+3)&3][1*4096 + dstoff]);                      \
    }                                                                                  \
    if (t_ <= 30){                                                                     \
      uint4 p0, p1;                                                                    \
      p0.x = f2bf(CUR[0].x) | (f2bf(CUR[0].y)<<16);                                    \
      p0.y = f2bf(CUR[0].z) | (f2bf(CUR[0].w)<<16);                                    \
      p0.z = f2bf(CUR[1].x) | (f2bf(CUR[1].y)<<16);                                    \
      p0.w = f2bf(CUR[1].z) | (f2bf(CUR[1].w)<<16);                                    \
      p1.x = f2bf(CUR[2].x) | (f2bf(CUR[2].y)<<16);                                    \
      p1.y = f2bf(CUR[2].z) | (f2bf(CUR[2].w)<<16);                                    \
      p1.z = f2bf(CUR[3].x) | (f2bf(CUR[3].y)<<16);                                    \
      p1.w = f2bf(CUR[3].z) | (f2bf(CUR[3].w)<<16);                                    \
      *(uint4*)(&ldsA[(t_+1)&1][0*4096 + w*512 + lane*8]) = p0;                        \
      *(uint4*)(&ldsA[(t_+1)&1][1*4096 + w*512 + lane*8]) = p1;                        \
    }                                                                                  \
    short8 bfr[4], afr[4], sfr = {};                                                   \
    bfr[0] = *(const short8*)(Bt + (wc*64 +  0)*32 + lane_off);                        \
    bfr[1] = *(const short8*)(Bt + (wc*64 + 16)*32 + lane_off);                        \
    bfr[2] = *(const short8*)(Bt + (wc*64 + 32)*32 + lane_off);                        \
    bfr[3] = *(const short8*)(Bt + (wc*64 + 48)*32 + lane_off);                        \
    afr[0] = *(const short8*)(At + (wr*128 +  0)*32 + lane_off);                       \
    afr[1] = *(const short8*)(At + (wr*128 + 16)*32 + lane_off);                       \
    afr[2] = *(const short8*)(At + (wr*128 + 32)*32 + lane_off);                       \
    afr[3] = *(const short8*)(At + (wr*128 + 48)*32 + lane_off);                       \
    if (act){                                                                          \
      sfr = *(const short8*)(&ldsS[hl*4096 + (t_&1)*2048 + wc*512 + lane_off]);        \
      if (!(t_ & 1)){                                                                  \
        const float4 iv = *(const float4*)&ldsAS[hl*64 + wc*16 + l4*4];                \
        f32x4 ivv; ivv[0]=iv.x; ivv[1]=iv.y; ivv[2]=iv.z; ivv[3]=iv.w;                 \
        acc2[0]=ivv; acc2[1]=ivv; acc2[2]=ivv; acc2[3]=ivv;                            \
        acc2[4]=ivv; acc2[5]=ivv; acc2[6]=ivv; acc2[7]=ivv;                            \
      }                                                                                \
    }                                                                                  \
    __builtin_amdgcn_s_setprio(1);                                                     \
    _Pragma("unroll")                                                                  \
    for (int i = 0; i < 4; ++i)                                                        \
      _Pragma("unroll")                                                                \
      for (int j = 0; j < 4; ++j)                                                      \
        acc[i][j] = __builtin_amdgcn_mfma_f32_16x16x32_bf16(bfr[j], afr[i], acc[i][j], 0, 0, 0); \
    if (act){                                                                          \
      acc2[0] = __builtin_amdgcn_mfma_f32_16x16x32_bf16(sfr, afr[0], acc2[0], 0, 0, 0);\
      acc2[1] = __builtin_amdgcn_mfma_f32_16x16x32_bf16(sfr, afr[1], acc2[1], 0, 0, 0);\
      acc2[2] = __builtin_amdgcn_mfma_f32_16x16x32_bf16(sfr, afr[2], acc2[2], 0, 0, 0);\
      acc2[3] = __builtin_amdgcn_mfma_f32_16x16x32_bf16(sfr, afr[3], acc2[3], 0, 0, 0);\
    }                                                                                  \
    __builtin_amdgcn_s_setprio(0);                                                     \
    afr[0] = *(const short8*)(At + (wr*128 +  64)*32 + lane_off);                      \
    afr[1] = *(const short8*)(At + (wr*128 +  80)*32 + lane_off);                      \
    afr[2] = *(const short8*)(At + (wr*128 +  96)*32 + lane_off);                      \
    afr[3] = *(const short8*)(At + (wr*128 + 112)*32 + lane_off);                      \
    __builtin_amdgcn_s_setprio(1);                                                     \
    _Pragma("unroll")                                                                  \
    for (int i = 0; i < 4; ++i)                                                        \
      _Pragma("unroll")                                                                \
      for (int j = 0; j < 4; ++j)                                                      \
        acc[4+i][j] = __builtin_amdgcn_mfma_f32_16x16x32_bf16(bfr[j], afr[i], acc[4+i][j], 0, 0, 0); \
    if (act){                                                                          \
      acc2[4] = __builtin_amdgcn_mfma_f32_16x16x32_bf16(sfr, afr[0], acc2[4], 0, 0, 0);\
      acc2[5] = __builtin_amdgcn_mfma_f32_16x16x32_bf16(sfr, afr[1], acc2[5], 0, 0, 0);\
      acc2[6] = __builtin_amdgcn_mfma_f32_16x16x32_bf16(sfr, afr[2], acc2[6], 0, 0, 0);\
      acc2[7] = __builtin_amdgcn_mfma_f32_16x16x32_bf16(sfr, afr[3], acc2[7], 0, 0, 0);\
    }                                                                                  \
    __builtin_amdgcn_s_setprio(0);                                                     \
    if (act && (t_ & 1)){                                                              \
      const size_t ob = (size_t)(t_ >> 1)*1048576 +                                    \
          ((size_t)bb*4096 + (bm & 4095) + wr*128 + l15)*64 + wc*16 + l4*4;            \
      _Pragma("unroll")                                                                \
      for (int i = 0; i < 8; ++i)                                                      \
        *(float4*)(out2 + ob + (size_t)i*1024) =                                       \
            make_float4(acc2[i][0], acc2[i][1], acc2[i][2], acc2[i][3]);               \
    }                                                                                  \
    if (t_ < 31){                                                                      \
      asm volatile("s_waitcnt lgkmcnt(0)" ::: "memory");                               \
      __builtin_amdgcn_s_barrier();                                                    \
      asm volatile("" ::: "memory");                                                   \
    }                                                                                  \
  }

  for (int tt = 0; tt < 16; ++tt){
    MEGA_TILE(2*tt,     rAb, rAa);
    MEGA_TILE(2*tt + 1, rAa, rAb);
  }
#undef MEGA_TILE

  // epilogue: main out (D cols l15 = t-row, regs = e-col)
  #pragma unroll
  for (int j = 0; j < 4; ++j){
    int n0 = bn + wc*64 + j*16 + l4*4;
    float4 cv = *(const float4*)&constb[bb*1024 + n0];
    #pragma unroll
    for (int i = 0; i < 8; ++i){
      int trow = bm + wr*128 + i*16 + l15;
      float4 o = make_float4(acc[i][j][0] + cv.x, acc[i][j][1] + cv.y,
                             acc[i][j][2] + cv.z, acc[i][j][3] + cv.w);
      *(float4*)(out + (size_t)trow*1024 + n0) = o;
    }
  }
}

extern "C" void kernel_launch(void* const* d_in, const int* in_sizes, int n_in,
                              void* d_out, int out_size, void* d_ws, size_t ws_size,
                              hipStream_t stream){
  const float* x     = (const float*)d_in[0];
  const float* state = (const float*)d_in[1];
  const float* A_w   = (const float*)d_in[2];
  const float* A_b   = (const float*)d_in[3];
  const float* C_w   = (const float*)d_in[4];
  const float* C_b   = (const float*)d_in[5];
  const float* sm    = (const float*)d_in[6];
  const float* Wo    = (const float*)d_in[7];
  const float* bo    = (const float*)d_in[8];
  float* out  = (float*)d_out;
  float* out2 = out + (size_t)MTz*Ez;

  char* ws = (char*)d_ws;
  float* a_state          = (float*)(ws + 0);                 //  16 KiB
  float* Mh               = (float*)(ws + 16384);             // 256 KiB
  float* bias_f           = (float*)(ws + 278528);            //  16 KiB
  float* constb           = (float*)(ws + 294912);            //  16 KiB
  unsigned short* Wb      = (unsigned short*)(ws + 311296);   //   2 MiB
  unsigned short* smB_g   = (unsigned short*)(ws + 2408448);  // 128 KiB

  k1_pre<<<64, 256, 0, stream>>>(state, A_w, A_b, C_w, C_b, sm, a_state, Mh, bias_f, smB_g);
  k23_pre<<<2048, 256, 0, stream>>>(Wo, Mh, bias_f, bo, Wb, constb);
  mega<<<256, 512, 0, stream>>>(x, Wb, smB_g, a_state, constb, out, out2);
}

// Round 12
// 99.519 us; speedup vs baseline: 2.6311x; 2.6311x over previous
//
#include <hip/hip_runtime.h>

#define Bz 4
#define Tz 4096
#define Ez 1024
#define Hz 16
#define Sz 64
#define Dz 64
#define MTz (Bz*Tz)   // 16384

using f32x4  = __attribute__((ext_vector_type(4))) float;
using short8 = __attribute__((ext_vector_type(8))) short;

__device__ __forceinline__ unsigned f2bf(float f){
  unsigned u = __builtin_bit_cast(unsigned, f);
  u = u + 0x7FFFu + ((u >> 16) & 1u);
  return (u >> 16);
}

#define GLL16(gp, lp) __builtin_amdgcn_global_load_lds( \
    (const __attribute__((address_space(1))) unsigned int*)(gp), \
    (__attribute__((address_space(3))) unsigned int*)(lp), 16, 0, 0)

// ---------------- K1 (64 blocks): Mh, a_state+bias_f ---------------------------------
__global__ __launch_bounds__(256) void k1_pre(const float* __restrict__ state,
                                              const float* __restrict__ A_w,
                                              const float* __restrict__ A_b,
                                              const float* __restrict__ C_w,
                                              const float* __restrict__ C_b,
                                              const float* __restrict__ sm,
                                              float* __restrict__ a_state,
                                              float* __restrict__ Mh,
                                              float* __restrict__ bias_f){
  __shared__ float asl[4][64];
  const int blk = blockIdx.x, tid = threadIdx.x;
  const int h = blk >> 2, q4 = blk & 3;
  { // Mh[h][d][dp] quarter
    const int d = q4*16 + (tid >> 4), dp0 = (tid & 15)*4;
    const float* cw  = C_w + (size_t)(h*64 + d)*64;
    const float* smh = sm + (size_t)h*4096 + dp0;
    float ax=0.f, ay=0.f, az=0.f, aw=0.f;
    #pragma unroll 8
    for (int s = 0; s < 64; ++s){
      float c = cw[s];
      float4 m4 = *(const float4*)&smh[s*64];
      ax += c*m4.x; ay += c*m4.y; az += c*m4.z; aw += c*m4.w;
    }
    *(float4*)&Mh[(size_t)h*4096 + d*64 + dp0] = make_float4(ax,ay,az,aw);
  }
  if (q4 == 0){
    { // a_state[h][b][s]
      const int b = tid >> 6, s = tid & 63;
      const float* aw = A_w + (size_t)(h*64 + s)*64;
      const float* st = state + (size_t)(h*4 + b)*64;
      float a0=A_b[h*64+s], a1=0.f, a2=0.f, a3=0.f;
      #pragma unroll 4
      for (int j = 0; j < 64; j += 4){
        a0 += aw[j]*st[j]; a1 += aw[j+1]*st[j+1];
        a2 += aw[j+2]*st[j+2]; a3 += aw[j+3]*st[j+3];
      }
      float v = (a0+a1)+(a2+a3);
      a_state[(h*4 + b)*64 + s] = v;
      asl[b][s] = v;
    }
    __syncthreads();
    { // bias_f[b][h*64+d]
      const int b = tid >> 6, d = tid & 63;
      const float* cw = C_w + (size_t)(h*64 + d)*64;
      float a0=C_b[h*64+d], a1=0.f, a2=0.f, a3=0.f;
      #pragma unroll 4
      for (int s = 0; s < 64; s += 4){
        a0 += cw[s]*asl[b][s]; a1 += cw[s+1]*asl[b][s+1];
        a2 += cw[s+2]*asl[b][s+2]; a3 += cw[s+3]*asl[b][s+3];
      }
      bias_f[b*1024 + h*64 + d] = (a0+a1)+(a2+a3);
    }
  }
}

// ---------------- K23 (2048 blocks): Wb (0..1023) ; constb (1024..2047) --------------
__global__ __launch_bounds__(256) void k23_pre(const float* __restrict__ Wo,
                                               const float* __restrict__ Mh,
                                               const float* __restrict__ bias_f,
                                               const float* __restrict__ bo,
                                               unsigned short* __restrict__ Wb,
                                               float* __restrict__ constb){
  const int blk = blockIdx.x, tid = threadIdx.x;
  if (blk < 1024){
    __shared__ float Mh_l[4096];
    const int h = blk >> 6, ec = blk & 63;
    #pragma unroll
    for (int it = 0; it < 4; ++it){
      int c = it*256 + tid;
      *(float4*)&Mh_l[c*4] = *(const float4*)&Mh[(size_t)h*4096 + c*4];
    }
    __syncthreads();
    const int dp = tid & 63, er = tid >> 6;
    #pragma unroll
    for (int ee = 0; ee < 4; ++ee){
      const int e = ec*16 + er*4 + ee;
      const float* wo = Wo + (size_t)e*1024 + h*64;
      float a0=0.f,a1=0.f,a2=0.f,a3=0.f;
      #pragma unroll 4
      for (int d = 0; d < 64; d += 4){
        a0 += wo[d]*Mh_l[d*64+dp];     a1 += wo[d+1]*Mh_l[(d+1)*64+dp];
        a2 += wo[d+2]*Mh_l[(d+2)*64+dp]; a3 += wo[d+3]*Mh_l[(d+3)*64+dp];
      }
      Wb[(size_t)e*1024 + h*64 + dp] = (unsigned short)f2bf((a0+a1)+(a2+a3));
    }
  } else {
    const int idx = (blk - 1024)*4 + (tid >> 6), lane = tid & 63;
    const int b = idx >> 10, e = idx & 1023;
    const float4* wo = (const float4*)(Wo + (size_t)e*1024);
    const float4* bf = (const float4*)(bias_f + (size_t)b*1024);
    float acc = 0.f;
    #pragma unroll
    for (int i = 0; i < 4; ++i){
      float4 w = wo[i*64 + lane], v = bf[i*64 + lane];
      acc += w.x*v.x + w.y*v.y + w.z*v.z + w.w*v.w;
    }
    acc += __shfl_down(acc, 32); acc += __shfl_down(acc, 16); acc += __shfl_down(acc, 8);
    acc += __shfl_down(acc, 4);  acc += __shfl_down(acc, 2);  acc += __shfl_down(acc, 1);
    if (lane == 0) constb[b*1024 + e] = bo[e] + acc;
  }
}

// ---------------- K4: new_state (MFMA, swapped operands) + emit xb=bf16(x) -----------
// grid: b(4) x h(16) x tb(32) = 2048 blocks, 256 thr, tile 128(t) x 64(s)
__global__ __launch_bounds__(256) void k4_ns(const float* __restrict__ x,
                                             const float* __restrict__ sm,
                                             const float* __restrict__ a_state,
                                             unsigned short* __restrict__ xb,
                                             float* __restrict__ out2){
  __shared__ alignas(16) unsigned short Xs[128*72];
  __shared__ alignas(16) unsigned short Ss[64*72];
  const int lin = blockIdx.x;
  const int tb = lin & 31, h = (lin >> 5) & 15, b = lin >> 9;
  const int tid = threadIdx.x;
  const int lane = tid & 63, w = tid >> 6;
  const int l15 = lane & 15, l4 = lane >> 4;

  { // stage sm[h] (f32) -> Ss bf16 (row stride 72)
    const float* src = sm + (size_t)h*4096;
    #pragma unroll
    for (int cc = 0; cc < 4; ++cc){
      int c = cc*256 + tid;                // 1024 chunks of 4 floats
      int s = c >> 4, c4 = c & 15;
      float4 v = *(const float4*)&src[s*64 + c4*4];
      uint2 pk = make_uint2(f2bf(v.x) | (f2bf(v.y)<<16), f2bf(v.z) | (f2bf(v.w)<<16));
      *(uint2*)&Ss[s*72 + c4*4] = pk;
    }
  }
  { // stage x slice -> Xs bf16 (stride 72) and xb global (row-major, 16B granules)
    const int row0 = b*Tz + tb*128;
    #pragma unroll
    for (int it = 0; it < 4; ++it){
      int id = it*256 + tid;               // 1024 chunks of 8 floats
      int r = id >> 3, c8 = id & 7;
      const float* px = x + (size_t)(row0 + r)*1024 + h*64 + c8*8;
      float4 v0 = *(const float4*)px, v1 = *(const float4*)(px + 4);
      uint4 pk;
      pk.x = f2bf(v0.x) | (f2bf(v0.y)<<16);
      pk.y = f2bf(v0.z) | (f2bf(v0.w)<<16);
      pk.z = f2bf(v1.x) | (f2bf(v1.y)<<16);
      pk.w = f2bf(v1.z) | (f2bf(v1.w)<<16);
      *(uint4*)&Xs[r*72 + c8*8] = pk;
      *(uint4*)(xb + (size_t)(row0 + r)*1024 + h*64 + c8*8) = pk;
    }
  }
  __syncthreads();

  // acc[i][j]: swapped layout -> D regs = s, D cols(l15) = t
  f32x4 acc[2][4];
  #pragma unroll
  for (int j = 0; j < 4; ++j){
    float4 as4 = *(const float4*)&a_state[(h*4 + b)*64 + j*16 + l4*4];
    f32x4 a0; a0[0]=as4.x; a0[1]=as4.y; a0[2]=as4.z; a0[3]=as4.w;
    acc[0][j] = a0; acc[1][j] = a0;
  }
  #pragma unroll
  for (int kk = 0; kk < 2; ++kk){
    short8 a[2], bb[4];
    #pragma unroll
    for (int i = 0; i < 2; ++i)
      a[i] = *(const short8*)(&Xs[(w*32 + i*16 + l15)*72 + kk*32 + l4*8]);
    #pragma unroll
    for (int j = 0; j < 4; ++j)
      bb[j] = *(const short8*)(&Ss[(j*16 + l15)*72 + kk*32 + l4*8]);
    #pragma unroll
    for (int i = 0; i < 2; ++i)
      #pragma unroll
      for (int j = 0; j < 4; ++j)
        acc[i][j] = __builtin_amdgcn_mfma_f32_16x16x32_bf16(bb[j], a[i], acc[i][j], 0, 0, 0);
  }
  const size_t base = (size_t)h*1048576 + ((size_t)b*4096 + tb*128)*64;
  #pragma unroll
  for (int i = 0; i < 2; ++i)
    #pragma unroll
    for (int j = 0; j < 4; ++j){
      float4 o = make_float4(acc[i][j][0], acc[i][j][1], acc[i][j][2], acc[i][j][3]);
      *(float4*)(out2 + base + (size_t)(w*32 + i*16 + l15)*64 + j*16 + l4*4) = o;
    }
}

// ---------------- K5: out = xb @ Wb^T + const  (R3/R9-proven schedule) ----------------
// 256x256 tile, BK=32, 512 thr (8 waves 2Mx4N), 4 LDS buffers, counted vmcnt(8),
// XOR-swizzled LDS: slot16 = (r*4+g) ^ (r&7)  (inverse applied on global source).
__global__ __launch_bounds__(512, 2) void k5_gemm(const unsigned short* __restrict__ xb,
                                                  const unsigned short* __restrict__ Wb,
                                                  const float* __restrict__ constb,
                                                  float* __restrict__ out){
  __shared__ alignas(16) unsigned short lds[4][2][8192];   // [buf][A/B][256 rows x 32 bf16]
  const int blk = blockIdx.x;
  const int swz = (blk & 7)*32 + (blk >> 3);     // 256 blocks, 8 XCD chunks of 32
  const int bm = (swz >> 2)*256, bn = (swz & 3)*256;
  const int tid = threadIdx.x;
  const int lane = tid & 63, w = tid >> 6;       // 8 waves
  const int l15 = lane & 15, l4 = lane >> 4;
  const int wr = w >> 2, wc = w & 3;             // 2 (M) x 4 (N)

  // staging source mapping: linear slot L -> logical (row r, 16B-seg g)
  const unsigned short* srcA[2];
  const unsigned short* srcB[2];
  #pragma unroll
  for (int q = 0; q < 2; ++q){
    int L = q*512 + w*64 + lane;
    int b = ((L>>2)&1) ^ ((L>>4)&1);
    int r = (L>>3)*2 + b;
    int g = (L&3) ^ ((((L>>3)&1)<<1) | b);
    srcA[q] = xb + (size_t)(bm + r)*1024 + g*8;
    srcB[q] = Wb + (size_t)(bn + r)*1024 + g*8;
  }
  const int dstoff = w*64*8;                      // shorts; + q*4096
  const int lane_off = ((l15*4 + l4) ^ (l15 & 7))*8;  // swizzled frag offset (shorts)

  // prologue: stage tiles 0,1,2 (12 GLL/thread)
  #pragma unroll
  for (int t = 0; t < 3; ++t){
    #pragma unroll
    for (int q = 0; q < 2; ++q) GLL16(srcA[q] + t*32, &lds[t][0][q*4096 + dstoff]);
    #pragma unroll
    for (int q = 0; q < 2; ++q) GLL16(srcB[q] + t*32, &lds[t][1][q*4096 + dstoff]);
  }
  asm volatile("s_waitcnt vmcnt(8)" ::: "memory");
  __builtin_amdgcn_s_barrier();
  asm volatile("" ::: "memory");

  f32x4 acc[8][4] = {};

  for (int t = 0; t < 32; ++t){
    const unsigned short* At = &lds[t & 3][0][0];
    const unsigned short* Bt = &lds[t & 3][1][0];
    const int ts = (t + 3) & 3;
    short8 bfr[4], afr[4];
    // ---- phase A: B-frags + A-frags 0..3, stage A of tile t+3, 16 MFMA
    #pragma unroll
    for (int j = 0; j < 4; ++j)
      bfr[j] = *(const short8*)(Bt + (wc*64 + j*16)*32 + lane_off);
    #pragma unroll
    for (int i = 0; i < 4; ++i)
      afr[i] = *(const short8*)(At + (wr*128 + i*16)*32 + lane_off);
    if (t < 29){
      #pragma unroll
      for (int q = 0; q < 2; ++q) GLL16(srcA[q] + (t+3)*32, &lds[ts][0][q*4096 + dstoff]);
    }
    __builtin_amdgcn_s_setprio(1);
    #pragma unroll
    for (int i = 0; i < 4; ++i)
      #pragma unroll
      for (int j = 0; j < 4; ++j)
        acc[i][j] = __builtin_amdgcn_mfma_f32_16x16x32_bf16(bfr[j], afr[i], acc[i][j], 0, 0, 0);
    __builtin_amdgcn_s_setprio(0);
    // ---- phase B: A-frags 4..7, stage B of tile t+3, 16 MFMA
    #pragma unroll
    for (int i = 0; i < 4; ++i)
      afr[i] = *(const short8*)(At + (wr*128 + (4 + i)*16)*32 + lane_off);
    if (t < 29){
      #pragma unroll
      for (int q = 0; q < 2; ++q) GLL16(srcB[q] + (t+3)*32, &lds[ts][1][q*4096 + dstoff]);
    }
    __builtin_amdgcn_s_setprio(1);
    #pragma unroll
    for (int i = 0; i < 4; ++i)
      #pragma unroll
      for (int j = 0; j < 4; ++j)
        acc[4+i][j] = __builtin_amdgcn_mfma_f32_16x16x32_bf16(bfr[j], afr[i], acc[4+i][j], 0, 0, 0);
    __builtin_amdgcn_s_setprio(0);
    // ---- tile boundary: counted vmcnt (tiles t+2,t+3 stay in flight), barrier
    if (t < 29)       asm volatile("s_waitcnt vmcnt(8)" ::: "memory");
    else if (t == 29) asm volatile("s_waitcnt vmcnt(4)" ::: "memory");
    else if (t == 30) asm volatile("s_waitcnt vmcnt(0)" ::: "memory");
    if (t < 31){
      __builtin_amdgcn_s_barrier();
      asm volatile("" ::: "memory");
    }
  }

  // epilogue: D cols(l15)=t-row, regs(l4*4+q)=e-col
  const int bb = bm >> 12;
  #pragma unroll
  for (int j = 0; j < 4; ++j){
    int n0 = bn + wc*64 + j*16 + l4*4;
    float4 cv = *(const float4*)&constb[bb*1024 + n0];
    #pragma unroll
    for (int i = 0; i < 8; ++i){
      int trow = bm + wr*128 + i*16 + l15;
      float4 o = make_float4(acc[i][j][0] + cv.x, acc[i][j][1] + cv.y,
                             acc[i][j][2] + cv.z, acc[i][j][3] + cv.w);
      *(float4*)(out + (size_t)trow*1024 + n0) = o;
    }
  }
}

extern "C" void kernel_launch(void* const* d_in, const int* in_sizes, int n_in,
                              void* d_out, int out_size, void* d_ws, size_t ws_size,
                              hipStream_t stream){
  const float* x     = (const float*)d_in[0];
  const float* state = (const float*)d_in[1];
  const float* A_w   = (const float*)d_in[2];
  const float* A_b   = (const float*)d_in[3];
  const float* C_w   = (const float*)d_in[4];
  const float* C_b   = (const float*)d_in[5];
  const float* sm    = (const float*)d_in[6];
  const float* Wo    = (const float*)d_in[7];
  const float* bo    = (const float*)d_in[8];
  float* out  = (float*)d_out;
  float* out2 = out + (size_t)MTz*Ez;

  char* ws = (char*)d_ws;
  float* a_state          = (float*)(ws + 0);                 //  16 KiB
  float* Mh               = (float*)(ws + 16384);             // 256 KiB
  float* bias_f           = (float*)(ws + 278528);            //  16 KiB
  float* constb           = (float*)(ws + 294912);            //  16 KiB
  unsigned short* Wb      = (unsigned short*)(ws + 311296);   //   2 MiB
  unsigned short* xb      = (unsigned short*)(ws + 2408448);  //  32 MiB

  k1_pre<<<64, 256, 0, stream>>>(state, A_w, A_b, C_w, C_b, sm, a_state, Mh, bias_f);
  k23_pre<<<2048, 256, 0, stream>>>(Wo, Mh, bias_f, bo, Wb, constb);
  k4_ns<<<2048, 256, 0, stream>>>(x, sm, a_state, xb, out2);
  k5_gemm<<<256, 512, 0, stream>>>(xb, Wb, constb, out);
}